// Round 1
// baseline (361.442 us; speedup 1.0000x reference)
//
#include <hip/hip_runtime.h>

#define HWD 256
#define HW2 (HWD * HWD)        // 65536 spatial positions per plane
#define NB 8                   // batch
#define NC 64                  // channels
#define PLANE4 (HW2 / 4)       // 16384 float4 per spatial plane

typedef float floatx4 __attribute__((ext_vector_type(4)));

// ---------------------------------------------------------------------------
// Kernel 1: channel-wise L1 norms for both inputs.
// Block = 256 threads = 64 spatial float4 positions x 4 waves, each wave owns
// 16 channels. LDS reduction across the 4 waves at the end.
// grid: NB * PLANE4/64 = 2048 blocks.
// CHANGE vs prev: explicit 4+4 float4 load batches. The previous version
// compiled to 36 VGPRs -> only ~2 loads in flight -> latency-bound at
// 2.7 TB/s effective (VALUBusy 3.4%). Arrays force 8 independent loads
// clustered ahead of the accumulate chain (~32 data VGPRs in flight).
// ---------------------------------------------------------------------------
__global__ void norms_kernel(const float* __restrict__ x1,
                             const float* __restrict__ x2,
                             float* __restrict__ n1,
                             float* __restrict__ n2) {
    const int s = threadIdx.x & 63;        // spatial float4 within tile
    const int g = threadIdx.x >> 6;        // wave id = channel group (0..3)
    const int blk = blockIdx.x;            // [0, NB*256)
    const int b = blk >> 8;                // batch
    const int p = ((blk & 255) << 6) + s;  // float4 index within plane

    const size_t base = (size_t)b * NC * PLANE4 + (size_t)g * 16 * PLANE4 + p;
    const float4* x1v = (const float4*)x1 + base;
    const float4* x2v = (const float4*)x2 + base;

    float4 a1 = make_float4(0.f, 0.f, 0.f, 0.f);
    float4 a2 = make_float4(0.f, 0.f, 0.f, 0.f);

#pragma unroll
    for (int c0 = 0; c0 < 16; c0 += 4) {
        float4 v1[4], v2[4];
#pragma unroll
        for (int j = 0; j < 4; ++j) v1[j] = x1v[(size_t)(c0 + j) * PLANE4];
#pragma unroll
        for (int j = 0; j < 4; ++j) v2[j] = x2v[(size_t)(c0 + j) * PLANE4];
#pragma unroll
        for (int j = 0; j < 4; ++j) {
            a1.x += fabsf(v1[j].x); a1.y += fabsf(v1[j].y);
            a1.z += fabsf(v1[j].z); a1.w += fabsf(v1[j].w);
            a2.x += fabsf(v2[j].x); a2.y += fabsf(v2[j].y);
            a2.z += fabsf(v2[j].z); a2.w += fabsf(v2[j].w);
        }
    }

    __shared__ float4 l1[4][64];
    __shared__ float4 l2[4][64];
    l1[g][s] = a1;
    l2[g][s] = a2;
    __syncthreads();

    // wave 0 reduces n1, wave 1 reduces n2
    const size_t oidx = (size_t)b * PLANE4 + p;
    if (g == 0) {
        float4 r0 = l1[0][s], r1 = l1[1][s], r2 = l1[2][s], r3 = l1[3][s];
        float4 o;
        o.x = (r0.x + r1.x) + (r2.x + r3.x);
        o.y = (r0.y + r1.y) + (r2.y + r3.y);
        o.z = (r0.z + r1.z) + (r2.z + r3.z);
        o.w = (r0.w + r1.w) + (r2.w + r3.w);
        ((float4*)n1)[oidx] = o;
    } else if (g == 1) {
        float4 r0 = l2[0][s], r1 = l2[1][s], r2 = l2[2][s], r3 = l2[3][s];
        float4 o;
        o.x = (r0.x + r1.x) + (r2.x + r3.x);
        o.y = (r0.y + r1.y) + (r2.y + r3.y);
        o.z = (r0.z + r1.z) + (r2.z + r3.z);
        o.w = (r0.w + r1.w) + (r2.w + r3.w);
        ((float4*)n2)[oidx] = o;
    }
}

// ---------------------------------------------------------------------------
// Kernel 2: 3x3 conv (zero pad, taps from w) + bias on n1,n2; emit
// r = c1 / (c1 + c2). float4-ized: each thread produces 4 consecutive
// outputs; per row it loads 1 aligned float4 + 2 boundary scalars per array.
// Working set (4 MiB in, 2 MiB out) is L2/L3-resident.
// grid: NB * HW2 / 4 / 256 = 512 blocks
// ---------------------------------------------------------------------------
__global__ void conv_ratio_kernel(const float* __restrict__ n1,
                                  const float* __restrict__ n2,
                                  const float* __restrict__ w,
                                  const float* __restrict__ bias,
                                  float* __restrict__ r) {
    int t = blockIdx.x * blockDim.x + threadIdx.x;   // [0, NB*HW2/4)
    int b = t >> 14;                                  // HW2/4 = 16384 per batch
    int sp = t & ((HW2 / 4) - 1);
    int y = sp >> 6;                                  // 64 float4 per row
    int x0 = (sp & 63) << 2;                          // leftmost pixel of the 4

    const float* p1 = n1 + (size_t)b * HW2;
    const float* p2 = n2 + (size_t)b * HW2;

    float o1[4] = {0.f, 0.f, 0.f, 0.f};
    float o2[4] = {0.f, 0.f, 0.f, 0.f};

#pragma unroll
    for (int dy = -1; dy <= 1; ++dy) {
        int yy = y + dy;
        if (yy < 0 || yy >= HWD) continue;   // zero pad
        const float* r1 = p1 + yy * HWD;
        const float* r2 = p2 + yy * HWD;
        float4 m1 = *(const float4*)(r1 + x0);
        float4 m2 = *(const float4*)(r2 + x0);
        float e1[6], e2[6];
        e1[0] = (x0 > 0) ? r1[x0 - 1] : 0.f;
        e2[0] = (x0 > 0) ? r2[x0 - 1] : 0.f;
        e1[1] = m1.x; e1[2] = m1.y; e1[3] = m1.z; e1[4] = m1.w;
        e2[1] = m2.x; e2[2] = m2.y; e2[3] = m2.z; e2[4] = m2.w;
        e1[5] = (x0 + 4 < HWD) ? r1[x0 + 4] : 0.f;
        e2[5] = (x0 + 4 < HWD) ? r2[x0 + 4] : 0.f;
        const float* wr = w + (dy + 1) * 3;
#pragma unroll
        for (int j = 0; j < 4; ++j) {
#pragma unroll
            for (int k = 0; k < 3; ++k) {
                o1[j] += wr[k] * e1[j + k];
                o2[j] += wr[k] * e2[j + k];
            }
        }
    }

    float bv = bias[0];
    float4 out;
    {
        float c1 = o1[0] + bv, c2 = o2[0] + bv; out.x = c1 / (c1 + c2);
    }
    {
        float c1 = o1[1] + bv, c2 = o2[1] + bv; out.y = c1 / (c1 + c2);
    }
    {
        float c1 = o1[2] + bv, c2 = o2[2] + bv; out.z = c1 / (c1 + c2);
    }
    {
        float c1 = o1[3] + bv, c2 = o2[3] + bv; out.w = c1 / (c1 + c2);
    }
    ((float4*)r)[t] = out;
}

// ---------------------------------------------------------------------------
// Kernel 3: out = x1 * r + x2 * (1 - r), r broadcast over channels.
// CHANGE vs prev: pure linear float4 streaming sweep (m13-copy style) instead
// of the channel-strided 8-iteration loop. r (256 KB/batch) is re-read from
// L2 instead of held in registers — the x1/x2/out streams become perfectly
// sequential. 4 fully-unrolled grid-stride iterations = 12 loads in flight.
// grid: 8192 blocks x 256 threads x 4 iters = 8,388,608 float4 (exact).
// ---------------------------------------------------------------------------
#define BLEND_BLOCKS 8192
#define BLEND_STRIDE ((size_t)BLEND_BLOCKS * 256)

__global__ void blend_kernel(const float* __restrict__ x1,
                             const float* __restrict__ x2,
                             const float* __restrict__ r,
                             float* __restrict__ out) {
    size_t idx = (size_t)blockIdx.x * 256 + threadIdx.x;
    const float4* x1v = (const float4*)x1;
    const float4* x2v = (const float4*)x2;
    const float4* rv4 = (const float4*)r;
    floatx4* ov = (floatx4*)out;

#pragma unroll
    for (int k = 0; k < 4; ++k) {
        size_t i = idx + (size_t)k * BLEND_STRIDE;
        int b = (int)(i >> 20);              // NC*PLANE4 = 2^20 float4/batch
        int p = (int)(i & (PLANE4 - 1));
        float4 rv = rv4[((size_t)b << 14) + p];
        float4 v1 = x1v[i];
        float4 v2 = x2v[i];
        floatx4 o;
        o.x = v1.x * rv.x + v2.x * (1.f - rv.x);
        o.y = v1.y * rv.y + v2.y * (1.f - rv.y);
        o.z = v1.z * rv.z + v2.z * (1.f - rv.z);
        o.w = v1.w * rv.w + v2.w * (1.f - rv.w);
        __builtin_nontemporal_store(o, ov + i);
    }
}

extern "C" void kernel_launch(void* const* d_in, const int* in_sizes, int n_in,
                              void* d_out, int out_size, void* d_ws, size_t ws_size,
                              hipStream_t stream) {
    const float* x1 = (const float*)d_in[0];
    const float* x2 = (const float*)d_in[1];
    const float* w  = (const float*)d_in[2];
    const float* bv = (const float*)d_in[3];
    float* out = (float*)d_out;

    // workspace layout: n1 | n2 | r, each NB*HW2 floats (2 MiB)
    float* n1 = (float*)d_ws;
    float* n2 = n1 + (size_t)NB * HW2;
    float* r  = n2 + (size_t)NB * HW2;

    const int block = 256;

    norms_kernel<<<NB * (PLANE4 / 64), block, 0, stream>>>(x1, x2, n1, n2);
    conv_ratio_kernel<<<NB * HW2 / 4 / block, block, 0, stream>>>(n1, n2, w, bv, r);
    blend_kernel<<<BLEND_BLOCKS, block, 0, stream>>>(x1, x2, r, out);
}